// Round 9
// baseline (2143.053 us; speedup 1.0000x reference)
//
#include <hip/hip_runtime.h>

#define N_NODES 50000
#define IN_DIM  256
#define OUT_DIM 128
#define NBINS   782      // bin = row >> 6  (64 rows per bin)
#define RPB     64
#define CHUNK   4096     // edges per partition block
#define EPT     16       // edges per thread in partition (CHUNK/256)
#define CAPBX   1408     // X edges per bin: mean 1024, +12 sigma
#define CAPBA   2600     // adj edges per bin: mean 2048, +12 sigma
#define CSTRIDE 8        // bin counters padded to one 32B sector

typedef unsigned long long u64;

// ---------------------------------------------------------------------------
// bf16 helpers (RNE).
// ---------------------------------------------------------------------------
__device__ __forceinline__ unsigned pack_bf16x2(float a, float b) {
    unsigned ua = __float_as_uint(a), ub = __float_as_uint(b);
    ua = (ua + 0x7fffu + ((ua >> 16) & 1u)) >> 16;
    ub = (ub + 0x7fffu + ((ub >> 16) & 1u)) >> 16;
    return ua | (ub << 16);
}
__device__ __forceinline__ float2 unpack_bf16x2(unsigned u) {
    return make_float2(__uint_as_float(u << 16),
                       __uint_as_float(u & 0xffff0000u));
}

// Edge word: [63:32] = f32 val bits, [31:16] = row, [15:0] = col.
// bin = row>>6 = bits [22..32) of the low word.

// ---------------------------------------------------------------------------
// Partition: LDS counting-sort each 4096-edge chunk by bin, allocate one
// global cursor atomic per (block, nonempty bin), write runs (~5 edges = 40B)
// contiguously.  Blocks [0,bx) handle X (with keep_prob=1 dropout, faithful);
// the rest handle adj.
// ---------------------------------------------------------------------------
__global__ __launch_bounds__(256) void partition(
        const int* __restrict__ xr, const int* __restrict__ xc,
        const float* __restrict__ xv, const float* __restrict__ dn, int nnz,
        const int* __restrict__ ar, const int* __restrict__ ac,
        const float* __restrict__ av, int ne,
        int* __restrict__ gcur_x, u64* __restrict__ egx,
        int* __restrict__ gcur_a, u64* __restrict__ ega, int bx) {
    __shared__ u64 stage[CHUNK];          // 32 KB
    __shared__ int hist[1024];            // zero-padded past NBINS
    __shared__ int base_l[1024];
    __shared__ int cur_l[1024];
    __shared__ int gbase[1024];
    __shared__ int tsum[256];

    int t = threadIdx.x;
    const int *rows, *cols;
    const float *vals, *noise = nullptr;
    int n, c0, cap;
    int* gcur;
    u64* eg;
    if (blockIdx.x < bx) {
        rows = xr; cols = xc; vals = xv; noise = dn; n = nnz;
        c0 = blockIdx.x * CHUNK; gcur = gcur_x; eg = egx; cap = CAPBX;
    } else {
        rows = ar; cols = ac; vals = av; n = ne;
        c0 = (blockIdx.x - bx) * CHUNK; gcur = gcur_a; eg = ega; cap = CAPBA;
    }

    for (int i = t; i < 1024; i += 256) hist[i] = 0;
    __syncthreads();

    u64 w[EPT];
    bool ok[EPT];
    #pragma unroll
    for (int j = 0; j < EPT; ++j) {
        int i = c0 + j * 256 + t;
        ok[j] = (i < n);
        if (ok[j]) {
            int r = rows[i], c = cols[i];
            float v = vals[i];
            if (noise) v *= floorf(1.0f + noise[i]);
            w[j] = ((u64)__float_as_uint(v) << 32) | ((unsigned)r << 16) | (unsigned)c;
            atomicAdd(&hist[r >> 6], 1);
        }
    }
    __syncthreads();

    // exclusive scan of hist (1024 entries, 4 per thread + Hillis-Steele)
    int s0 = hist[t * 4], s1 = hist[t * 4 + 1], s2 = hist[t * 4 + 2], s3 = hist[t * 4 + 3];
    int tot = s0 + s1 + s2 + s3;
    tsum[t] = tot;
    __syncthreads();
    for (int off = 1; off < 256; off <<= 1) {
        int v = (t >= off) ? tsum[t - off] : 0;
        __syncthreads();
        tsum[t] += v;
        __syncthreads();
    }
    int pfx = tsum[t] - tot;
    base_l[t * 4]     = pfx;
    base_l[t * 4 + 1] = pfx + s0;
    base_l[t * 4 + 2] = pfx + s0 + s1;
    base_l[t * 4 + 3] = pfx + s0 + s1 + s2;
    cur_l[t * 4]     = base_l[t * 4];
    cur_l[t * 4 + 1] = base_l[t * 4 + 1];
    cur_l[t * 4 + 2] = base_l[t * 4 + 2];
    cur_l[t * 4 + 3] = base_l[t * 4 + 3];
    __syncthreads();

    // one global cursor atomic per nonempty bin
    for (int i = t; i < NBINS; i += 256) {
        int c = hist[i];
        if (c) gbase[i] = atomicAdd(&gcur[i * CSTRIDE], c);
    }
    // scatter into LDS staging (sorted by bin)
    #pragma unroll
    for (int j = 0; j < EPT; ++j) {
        if (ok[j]) {
            int b = (int)((w[j] >> 22) & 0x3ff);
            int p = atomicAdd(&cur_l[b], 1);
            stage[p] = w[j];
        }
    }
    __syncthreads();

    // coalesced run write-out
    int cnt = min(n - c0, CHUNK);
    for (int p = t; p < cnt; p += 256) {
        u64 ww = stage[p];
        int b = (int)((ww >> 22) & 0x3ff);
        int g = gbase[b] + (p - base_l[b]);
        if (g < cap) eg[(size_t)b * cap + g] = ww;
    }
}

// ---------------------------------------------------------------------------
// SpMM 1: h(bf16) = X * W.  Block per bin; 64x128 f32 accumulator in LDS.
// Per edge: wave gathers W row (lane -> dims lane, lane+64), 2 ds_add_f32
// per lane (bank-conflict-free).  hpk word j of row g = bf16(h[g][j], h[g][j+64]).
// ---------------------------------------------------------------------------
__global__ __launch_bounds__(256) void spmm_x_lds(const int* __restrict__ gcur,
                                                  const u64* __restrict__ eg,
                                                  const float* __restrict__ W,
                                                  unsigned* __restrict__ hpk) {
    __shared__ float acc[RPB * 128];   // 32 KB
    int t = threadIdx.x;
    for (int i = t; i < RPB * 128; i += 256) acc[i] = 0.0f;
    __syncthreads();

    int bin = blockIdx.x;
    int cnt = min(gcur[bin * CSTRIDE], CAPBX);
    size_t base = (size_t)bin * CAPBX;
    int lane = t & 63, wv = t >> 6;
    int per = (cnt + 3) >> 2;
    int s = wv * per, e1 = min(s + per, cnt);

    int e = s;
    for (; e + 3 < e1; e += 4) {
        u64 w0 = eg[base + e], w1 = eg[base + e + 1];
        u64 w2 = eg[base + e + 2], w3 = eg[base + e + 3];
        int c0 = (int)(w0 & 0xffffu), c1 = (int)(w1 & 0xffffu);
        int c2 = (int)(w2 & 0xffffu), c3 = (int)(w3 & 0xffffu);
        float a0 = W[(size_t)c0 * 128 + lane], b0 = W[(size_t)c0 * 128 + 64 + lane];
        float a1 = W[(size_t)c1 * 128 + lane], b1 = W[(size_t)c1 * 128 + 64 + lane];
        float a2 = W[(size_t)c2 * 128 + lane], b2 = W[(size_t)c2 * 128 + 64 + lane];
        float a3 = W[(size_t)c3 * 128 + lane], b3 = W[(size_t)c3 * 128 + 64 + lane];
        float v0 = __uint_as_float((unsigned)(w0 >> 32));
        float v1 = __uint_as_float((unsigned)(w1 >> 32));
        float v2 = __uint_as_float((unsigned)(w2 >> 32));
        float v3 = __uint_as_float((unsigned)(w3 >> 32));
        int r0 = (int)((w0 >> 16) & 63), r1 = (int)((w1 >> 16) & 63);
        int r2 = (int)((w2 >> 16) & 63), r3 = (int)((w3 >> 16) & 63);
        atomicAdd(&acc[r0 * 128 + lane], v0 * a0);
        atomicAdd(&acc[r0 * 128 + 64 + lane], v0 * b0);
        atomicAdd(&acc[r1 * 128 + lane], v1 * a1);
        atomicAdd(&acc[r1 * 128 + 64 + lane], v1 * b1);
        atomicAdd(&acc[r2 * 128 + lane], v2 * a2);
        atomicAdd(&acc[r2 * 128 + 64 + lane], v2 * b2);
        atomicAdd(&acc[r3 * 128 + lane], v3 * a3);
        atomicAdd(&acc[r3 * 128 + 64 + lane], v3 * b3);
    }
    for (; e < e1; ++e) {
        u64 w0 = eg[base + e];
        int c0 = (int)(w0 & 0xffffu);
        float a0 = W[(size_t)c0 * 128 + lane], b0 = W[(size_t)c0 * 128 + 64 + lane];
        float v0 = __uint_as_float((unsigned)(w0 >> 32));
        int r0 = (int)((w0 >> 16) & 63);
        atomicAdd(&acc[r0 * 128 + lane], v0 * a0);
        atomicAdd(&acc[r0 * 128 + 64 + lane], v0 * b0);
    }
    __syncthreads();

    int g0 = bin * RPB;
    for (int i = t; i < RPB * 64; i += 256) {
        int r = i >> 6, j = i & 63;
        int g = g0 + r;
        if (g < N_NODES)
            hpk[(size_t)g * 64 + j] = pack_bf16x2(acc[r * 128 + j], acc[r * 128 + 64 + j]);
    }
}

// ---------------------------------------------------------------------------
// SpMM 2 + ReLU: out = relu(A * h).  Block per bin; 64x128 f32 LDS acc;
// per edge wave gathers packed-bf16 h row (256 B coalesced).
// ---------------------------------------------------------------------------
__global__ __launch_bounds__(256) void spmm_a_lds(const int* __restrict__ gcur,
                                                  const u64* __restrict__ eg,
                                                  const unsigned* __restrict__ hpk,
                                                  float* __restrict__ out) {
    __shared__ float acc[RPB * 128];   // 32 KB
    int t = threadIdx.x;
    for (int i = t; i < RPB * 128; i += 256) acc[i] = 0.0f;
    __syncthreads();

    int bin = blockIdx.x;
    int cnt = min(gcur[bin * CSTRIDE], CAPBA);
    size_t base = (size_t)bin * CAPBA;
    int lane = t & 63, wv = t >> 6;
    int per = (cnt + 3) >> 2;
    int s = wv * per, e1 = min(s + per, cnt);

    int e = s;
    for (; e + 3 < e1; e += 4) {
        u64 w0 = eg[base + e], w1 = eg[base + e + 1];
        u64 w2 = eg[base + e + 2], w3 = eg[base + e + 3];
        int c0 = (int)(w0 & 0xffffu), c1 = (int)(w1 & 0xffffu);
        int c2 = (int)(w2 & 0xffffu), c3 = (int)(w3 & 0xffffu);
        unsigned u0 = hpk[(size_t)c0 * 64 + lane];
        unsigned u1 = hpk[(size_t)c1 * 64 + lane];
        unsigned u2 = hpk[(size_t)c2 * 64 + lane];
        unsigned u3 = hpk[(size_t)c3 * 64 + lane];
        float v0 = __uint_as_float((unsigned)(w0 >> 32));
        float v1 = __uint_as_float((unsigned)(w1 >> 32));
        float v2 = __uint_as_float((unsigned)(w2 >> 32));
        float v3 = __uint_as_float((unsigned)(w3 >> 32));
        int r0 = (int)((w0 >> 16) & 63), r1 = (int)((w1 >> 16) & 63);
        int r2 = (int)((w2 >> 16) & 63), r3 = (int)((w3 >> 16) & 63);
        float2 h0 = unpack_bf16x2(u0), h1 = unpack_bf16x2(u1);
        float2 h2 = unpack_bf16x2(u2), h3 = unpack_bf16x2(u3);
        atomicAdd(&acc[r0 * 128 + lane], v0 * h0.x);
        atomicAdd(&acc[r0 * 128 + 64 + lane], v0 * h0.y);
        atomicAdd(&acc[r1 * 128 + lane], v1 * h1.x);
        atomicAdd(&acc[r1 * 128 + 64 + lane], v1 * h1.y);
        atomicAdd(&acc[r2 * 128 + lane], v2 * h2.x);
        atomicAdd(&acc[r2 * 128 + 64 + lane], v2 * h2.y);
        atomicAdd(&acc[r3 * 128 + lane], v3 * h3.x);
        atomicAdd(&acc[r3 * 128 + 64 + lane], v3 * h3.y);
    }
    for (; e < e1; ++e) {
        u64 w0 = eg[base + e];
        int c0 = (int)(w0 & 0xffffu);
        float2 h0 = unpack_bf16x2(hpk[(size_t)c0 * 64 + lane]);
        float v0 = __uint_as_float((unsigned)(w0 >> 32));
        int r0 = (int)((w0 >> 16) & 63);
        atomicAdd(&acc[r0 * 128 + lane], v0 * h0.x);
        atomicAdd(&acc[r0 * 128 + 64 + lane], v0 * h0.y);
    }
    __syncthreads();

    int g0 = bin * RPB;
    for (int i = t; i < RPB * 128; i += 256) {
        int r = i >> 7;
        int g = g0 + r;
        if (g < N_NODES)
            out[(size_t)g * 128 + (i & 127)] = fmaxf(acc[i], 0.0f);
    }
}

extern "C" void kernel_launch(void* const* d_in, const int* in_sizes, int n_in,
                              void* d_out, int out_size, void* d_ws, size_t ws_size,
                              hipStream_t stream) {
    const int*   x_rows     = (const int*)d_in[0];
    const int*   x_cols     = (const int*)d_in[1];
    const float* x_vals     = (const float*)d_in[2];
    const float* drop_noise = (const float*)d_in[3];
    const int*   adj_rows   = (const int*)d_in[4];
    const int*   adj_cols   = (const int*)d_in[5];
    const float* adj_vals   = (const float*)d_in[6];
    const float* W          = (const float*)d_in[7];

    const int nnz = in_sizes[0];   // 800000
    const int ne  = in_sizes[4];   // 1600000

    float* out = (float*)d_out;

    // ---- workspace layout (~38 MB) -----------------------------------------
    char* base = (char*)d_ws;
    unsigned* hpk = (unsigned*)base;                               // 12.8 MB
    u64* egx = (u64*)(base + (size_t)N_NODES * 64 * sizeof(unsigned));  // 8.8 MB
    u64* ega = egx + (size_t)NBINS * CAPBX;                        // 16.3 MB
    int* gcur_x = (int*)(ega + (size_t)NBINS * CAPBA);             // 25 KB
    int* gcur_a = gcur_x + NBINS * CSTRIDE;                        // 25 KB

    hipMemsetAsync(gcur_x, 0, 2 * (size_t)NBINS * CSTRIDE * sizeof(int), stream);

    const int BXC = (nnz + CHUNK - 1) / CHUNK;   // 196
    const int BAC = (ne + CHUNK - 1) / CHUNK;    // 391

    partition<<<BXC + BAC, 256, 0, stream>>>(
        x_rows, x_cols, x_vals, drop_noise, nnz,
        adj_rows, adj_cols, adj_vals, ne,
        gcur_x, egx, gcur_a, ega, BXC);

    spmm_x_lds<<<NBINS, 256, 0, stream>>>(gcur_x, egx, W, hpk);

    spmm_a_lds<<<NBINS, 256, 0, stream>>>(gcur_a, ega, hpk, out);
}

// Round 10
// 226.334 us; speedup vs baseline: 9.4685x; 9.4685x over previous
//
#include <hip/hip_runtime.h>

#define N_NODES 50000
#define IN_DIM  256
#define OUT_DIM 128
#define OD2     64       // packed bf16 pairs / float2 per 128-dim row
#define NBINS   782      // bin = row >> 6  (64 rows per bin)
#define RPB     64
#define CHUNK   4096     // edges per partition block
#define EPT     16       // edges per thread in partition (CHUNK/256)
#define CAPBX   1408     // X edges per bin: mean 1024, +12 sigma
#define CAPBA   2600     // adj edges per bin: mean 2048, +12 sigma
#define CSTRIDE 8        // bin counters padded to one 32B sector

typedef unsigned long long u64;

// ---------------------------------------------------------------------------
// bf16 helpers (RNE).
// ---------------------------------------------------------------------------
__device__ __forceinline__ unsigned pack_bf16x2(float a, float b) {
    unsigned ua = __float_as_uint(a), ub = __float_as_uint(b);
    ua = (ua + 0x7fffu + ((ua >> 16) & 1u)) >> 16;
    ub = (ub + 0x7fffu + ((ub >> 16) & 1u)) >> 16;
    return ua | (ub << 16);
}
__device__ __forceinline__ float2 unpack_bf16x2(unsigned u) {
    return make_float2(__uint_as_float(u << 16),
                       __uint_as_float(u & 0xffff0000u));
}

// Edge word (u64): [63:32] = f32 val bits, [31:16] = row, [15:0] = col.
// Packed edge (u32): [31:16] = bf16 val bits, [15:0] = col.

// ---------------------------------------------------------------------------
// Level 1: partition into 782 row-bins.  LDS counting-sort each 4096-edge
// chunk by bin, one global cursor atomic per (block, nonempty bin), write
// runs contiguously (coalesced).  Blocks [0,bx) = X (keep_prob=1 dropout,
// faithful); rest = adj.
// ---------------------------------------------------------------------------
__global__ __launch_bounds__(256) void partition(
        const int* __restrict__ xr, const int* __restrict__ xc,
        const float* __restrict__ xv, const float* __restrict__ dn, int nnz,
        const int* __restrict__ ar, const int* __restrict__ ac,
        const float* __restrict__ av, int ne,
        int* __restrict__ gcur_x, u64* __restrict__ egx,
        int* __restrict__ gcur_a, u64* __restrict__ ega, int bx) {
    __shared__ u64 stage[CHUNK];          // 32 KB
    __shared__ int hist[1024];            // zero-padded past NBINS
    __shared__ int base_l[1024];
    __shared__ int cur_l[1024];
    __shared__ int gbase[1024];
    __shared__ int tsum[256];

    int t = threadIdx.x;
    const int *rows, *cols;
    const float *vals, *noise = nullptr;
    int n, c0, cap;
    int* gcur;
    u64* eg;
    if (blockIdx.x < bx) {
        rows = xr; cols = xc; vals = xv; noise = dn; n = nnz;
        c0 = blockIdx.x * CHUNK; gcur = gcur_x; eg = egx; cap = CAPBX;
    } else {
        rows = ar; cols = ac; vals = av; n = ne;
        c0 = (blockIdx.x - bx) * CHUNK; gcur = gcur_a; eg = ega; cap = CAPBA;
    }

    for (int i = t; i < 1024; i += 256) hist[i] = 0;
    __syncthreads();

    u64 w[EPT];
    bool ok[EPT];
    #pragma unroll
    for (int j = 0; j < EPT; ++j) {
        int i = c0 + j * 256 + t;
        ok[j] = (i < n);
        if (ok[j]) {
            int r = rows[i], c = cols[i];
            float v = vals[i];
            if (noise) v *= floorf(1.0f + noise[i]);
            w[j] = ((u64)__float_as_uint(v) << 32) | ((unsigned)r << 16) | (unsigned)c;
            atomicAdd(&hist[r >> 6], 1);
        }
    }
    __syncthreads();

    // exclusive scan of hist (1024 entries, 4/thread + Hillis-Steele)
    int s0 = hist[t * 4], s1 = hist[t * 4 + 1], s2 = hist[t * 4 + 2], s3 = hist[t * 4 + 3];
    int tot = s0 + s1 + s2 + s3;
    tsum[t] = tot;
    __syncthreads();
    for (int off = 1; off < 256; off <<= 1) {
        int v = (t >= off) ? tsum[t - off] : 0;
        __syncthreads();
        tsum[t] += v;
        __syncthreads();
    }
    int pfx = tsum[t] - tot;
    base_l[t * 4]     = pfx;
    base_l[t * 4 + 1] = pfx + s0;
    base_l[t * 4 + 2] = pfx + s0 + s1;
    base_l[t * 4 + 3] = pfx + s0 + s1 + s2;
    cur_l[t * 4]     = base_l[t * 4];
    cur_l[t * 4 + 1] = base_l[t * 4 + 1];
    cur_l[t * 4 + 2] = base_l[t * 4 + 2];
    cur_l[t * 4 + 3] = base_l[t * 4 + 3];
    __syncthreads();

    // one global cursor atomic per nonempty bin
    for (int i = t; i < NBINS; i += 256) {
        int c = hist[i];
        if (c) gbase[i] = atomicAdd(&gcur[i * CSTRIDE], c);
    }
    // scatter into LDS staging (sorted by bin)
    #pragma unroll
    for (int j = 0; j < EPT; ++j) {
        if (ok[j]) {
            int b = (int)((w[j] >> 22) & 0x3ff);
            int p = atomicAdd(&cur_l[b], 1);
            stage[p] = w[j];
        }
    }
    __syncthreads();

    // coalesced run write-out
    int cnt = min(n - c0, CHUNK);
    for (int p = t; p < cnt; p += 256) {
        u64 ww = stage[p];
        int b = (int)((ww >> 22) & 0x3ff);
        int g = gbase[b] + (p - base_l[b]);
        if (g < cap) eg[(size_t)b * cap + g] = ww;
    }
}

// ---------------------------------------------------------------------------
// Level 2: row-sort within each bin -> exact per-row CSR segments (no per-row
// caps), repacked to 4 B edges, fully coalesced writes.
// Grid = 2*NBINS: blocks [0,NBINS) = X, rest = adj.
// ---------------------------------------------------------------------------
__global__ __launch_bounds__(256) void rowsort(
        const int* __restrict__ gcur_x, const u64* __restrict__ egx,
        unsigned* __restrict__ e4x, int* __restrict__ rptr_x, int* __restrict__ rcnt_x,
        const int* __restrict__ gcur_a, const u64* __restrict__ ega,
        unsigned* __restrict__ e4a, int* __restrict__ rptr_a, int* __restrict__ rcnt_a) {
    __shared__ u64 stage[CAPBA];        // 20.8 KB
    __shared__ unsigned sorted[CAPBA];  // 10.4 KB
    __shared__ int hist[64], ptrl[64], curl[64];

    int t = threadIdx.x;
    int bin, cap;
    const u64* eg;
    unsigned* e4;
    int *rptr, *rcnt;
    int cnt;
    if (blockIdx.x < NBINS) {
        bin = blockIdx.x; cap = CAPBX; eg = egx; e4 = e4x;
        rptr = rptr_x; rcnt = rcnt_x;
        cnt = min(gcur_x[bin * CSTRIDE], cap);
    } else {
        bin = blockIdx.x - NBINS; cap = CAPBA; eg = ega; e4 = e4a;
        rptr = rptr_a; rcnt = rcnt_a;
        cnt = min(gcur_a[bin * CSTRIDE], cap);
    }
    size_t base = (size_t)bin * cap;

    for (int i = t; i < cnt; i += 256) stage[i] = eg[base + i];
    if (t < 64) hist[t] = 0;
    __syncthreads();

    for (int i = t; i < cnt; i += 256)
        atomicAdd(&hist[(int)((stage[i] >> 16) & 63)], 1);
    __syncthreads();

    if (t == 0) {                         // 64-entry serial scan, trivial
        int s = 0;
        for (int r = 0; r < 64; ++r) { ptrl[r] = s; s += hist[r]; }
    }
    __syncthreads();
    if (t < 64) curl[t] = ptrl[t];
    __syncthreads();

    for (int i = t; i < cnt; i += 256) {
        u64 w = stage[i];
        int r = (int)((w >> 16) & 63);
        int p = atomicAdd(&curl[r], 1);
        unsigned uv = (unsigned)(w >> 32);
        uv = (uv + 0x7fffu + ((uv >> 16) & 1u)) & 0xffff0000u;   // bf16 in hi16
        sorted[p] = (unsigned)(w & 0xffffu) | uv;
    }
    __syncthreads();

    for (int i = t; i < cnt; i += 256) e4[base + i] = sorted[i];
    if (t < 64) {
        int g = bin * RPB + t;
        if (g < N_NODES) {
            rptr[g] = (int)base + ptrl[t];
            rcnt[g] = hist[t];
        }
    }
}

// ---------------------------------------------------------------------------
// SpMM 1: h(bf16) = X * W.  One wave per row; lane owns dims {2l,2l+1};
// W gathered as float2 from global (128 KB -> L2-resident); 4-way unroll.
// ---------------------------------------------------------------------------
__global__ void spmm_w(const int* __restrict__ rptr, const int* __restrict__ rcnt,
                       const unsigned* __restrict__ e4,
                       const float2* __restrict__ Wt, unsigned* __restrict__ hpk,
                       int nrows) {
    int wave = (blockIdx.x * blockDim.x + threadIdx.x) >> 6;
    int lane = threadIdx.x & 63;
    if (wave >= nrows) return;

    int s   = rptr[wave];
    int end = s + rcnt[wave];
    float2 acc = make_float2(0.0f, 0.0f);

    int e = s;
    for (; e + 3 < end; e += 4) {
        unsigned u0 = e4[e], u1 = e4[e + 1], u2 = e4[e + 2], u3 = e4[e + 3];
        float2 a = Wt[(size_t)(u0 & 0xffffu) * OD2 + lane];
        float2 b = Wt[(size_t)(u1 & 0xffffu) * OD2 + lane];
        float2 c = Wt[(size_t)(u2 & 0xffffu) * OD2 + lane];
        float2 d = Wt[(size_t)(u3 & 0xffffu) * OD2 + lane];
        float v0 = __uint_as_float(u0 & 0xffff0000u);
        float v1 = __uint_as_float(u1 & 0xffff0000u);
        float v2 = __uint_as_float(u2 & 0xffff0000u);
        float v3 = __uint_as_float(u3 & 0xffff0000u);
        acc.x += v0 * a.x + v1 * b.x + v2 * c.x + v3 * d.x;
        acc.y += v0 * a.y + v1 * b.y + v2 * c.y + v3 * d.y;
    }
    for (; e < end; ++e) {
        unsigned u0 = e4[e];
        float2 a = Wt[(size_t)(u0 & 0xffffu) * OD2 + lane];
        float v0 = __uint_as_float(u0 & 0xffff0000u);
        acc.x += v0 * a.x;
        acc.y += v0 * a.y;
    }
    hpk[(size_t)wave * OD2 + lane] = pack_bf16x2(acc.x, acc.y);
}

// ---------------------------------------------------------------------------
// SpMM 2 + ReLU: out = relu(A * h).  One wave per row; gathers packed-bf16
// h rows (256 B/row, coalesced); f32 accumulate; f32 out.
// ---------------------------------------------------------------------------
__global__ void spmm_h(const int* __restrict__ rptr, const int* __restrict__ rcnt,
                       const unsigned* __restrict__ e4,
                       const unsigned* __restrict__ hpk, float2* __restrict__ outm,
                       int nrows) {
    int wave = (blockIdx.x * blockDim.x + threadIdx.x) >> 6;
    int lane = threadIdx.x & 63;
    if (wave >= nrows) return;

    int s   = rptr[wave];
    int end = s + rcnt[wave];
    float2 acc = make_float2(0.0f, 0.0f);

    int e = s;
    for (; e + 3 < end; e += 4) {
        unsigned u0 = e4[e], u1 = e4[e + 1], u2 = e4[e + 2], u3 = e4[e + 3];
        unsigned h0 = hpk[(size_t)(u0 & 0xffffu) * OD2 + lane];
        unsigned h1 = hpk[(size_t)(u1 & 0xffffu) * OD2 + lane];
        unsigned h2 = hpk[(size_t)(u2 & 0xffffu) * OD2 + lane];
        unsigned h3 = hpk[(size_t)(u3 & 0xffffu) * OD2 + lane];
        float v0 = __uint_as_float(u0 & 0xffff0000u);
        float v1 = __uint_as_float(u1 & 0xffff0000u);
        float v2 = __uint_as_float(u2 & 0xffff0000u);
        float v3 = __uint_as_float(u3 & 0xffff0000u);
        float2 a = unpack_bf16x2(h0), b = unpack_bf16x2(h1);
        float2 c = unpack_bf16x2(h2), d = unpack_bf16x2(h3);
        acc.x += v0 * a.x + v1 * b.x + v2 * c.x + v3 * d.x;
        acc.y += v0 * a.y + v1 * b.y + v2 * c.y + v3 * d.y;
    }
    for (; e < end; ++e) {
        unsigned u0 = e4[e];
        float2 a = unpack_bf16x2(hpk[(size_t)(u0 & 0xffffu) * OD2 + lane]);
        float v0 = __uint_as_float(u0 & 0xffff0000u);
        acc.x += v0 * a.x;
        acc.y += v0 * a.y;
    }
    acc.x = fmaxf(acc.x, 0.0f);
    acc.y = fmaxf(acc.y, 0.0f);
    outm[(size_t)wave * OD2 + lane] = acc;
}

extern "C" void kernel_launch(void* const* d_in, const int* in_sizes, int n_in,
                              void* d_out, int out_size, void* d_ws, size_t ws_size,
                              hipStream_t stream) {
    const int*   x_rows     = (const int*)d_in[0];
    const int*   x_cols     = (const int*)d_in[1];
    const float* x_vals     = (const float*)d_in[2];
    const float* drop_noise = (const float*)d_in[3];
    const int*   adj_rows   = (const int*)d_in[4];
    const int*   adj_cols   = (const int*)d_in[5];
    const float* adj_vals   = (const float*)d_in[6];
    const float* W          = (const float*)d_in[7];

    const int nnz = in_sizes[0];   // 800000
    const int ne  = in_sizes[4];   // 1600000

    float* out = (float*)d_out;

    // ---- workspace layout (~52 MB) -----------------------------------------
    char* base = (char*)d_ws;
    unsigned* hpk = (unsigned*)base;                                    // 12.8 MB
    u64* egx = (u64*)(base + (size_t)N_NODES * OD2 * sizeof(unsigned)); // 8.8 MB
    u64* ega = egx + (size_t)NBINS * CAPBX;                             // 16.3 MB
    unsigned* e4x = (unsigned*)(ega + (size_t)NBINS * CAPBA);           // 4.4 MB
    unsigned* e4a = e4x + (size_t)NBINS * CAPBX;                        // 8.1 MB
    int* rptr_x = (int*)(e4a + (size_t)NBINS * CAPBA);                  // 200 KB
    int* rcnt_x = rptr_x + N_NODES;
    int* rptr_a = rcnt_x + N_NODES;
    int* rcnt_a = rptr_a + N_NODES;
    int* gcur_x = rcnt_a + N_NODES;                                     // 25 KB
    int* gcur_a = gcur_x + NBINS * CSTRIDE;

    hipMemsetAsync(gcur_x, 0, 2 * (size_t)NBINS * CSTRIDE * sizeof(int), stream);

    const int BXC = (nnz + CHUNK - 1) / CHUNK;   // 196
    const int BAC = (ne + CHUNK - 1) / CHUNK;    // 391

    // L1: bin partition (coalesced run writes)
    partition<<<BXC + BAC, 256, 0, stream>>>(
        x_rows, x_cols, x_vals, drop_noise, nnz,
        adj_rows, adj_cols, adj_vals, ne,
        gcur_x, egx, gcur_a, ega, BXC);

    // L2: exact per-row CSR within bins, 4 B packed edges, coalesced
    rowsort<<<2 * NBINS, 256, 0, stream>>>(
        gcur_x, egx, e4x, rptr_x, rcnt_x,
        gcur_a, ega, e4a, rptr_a, rcnt_a);

    // SpMM 1: h(bf16) = X * W
    int blocks_spmm = (N_NODES * 64 + 255) / 256;   // one wave per row
    spmm_w<<<blocks_spmm, 256, 0, stream>>>(rptr_x, rcnt_x, e4x,
                                            (const float2*)W, hpk, N_NODES);

    // SpMM 2 + ReLU: out = relu(A * h)
    spmm_h<<<blocks_spmm, 256, 0, stream>>>(rptr_a, rcnt_a, e4a, hpk,
                                            (float2*)out, N_NODES);
}